// Round 5
// baseline (269.907 us; speedup 1.0000x reference)
//
#include <hip/hip_runtime.h>
#include <stdint.h>
#include <stddef.h>

// LSTMCell fused: z = [h|x] @ [Wh|Wx]^T + (Wh_b+Wx_b); s=sigmoid(z); g=tanh(z);
// c_new = s*(c+g); h_new = s*tanh(c_new). Outputs concat [h_new, c_new] fp32.
// B=8192, D_H=D_IN=1024, K_total=2048.
//
// GEMM: BM=256 x BN=128 x BK=64, 512 thr = 8 waves as 2M x 2N x 2K.
// Each wave: 128x64 output tile, one 32-wide kk-half per K-tile ->
// 12 ds_read_b128 + 32 MFMA per kt in ONE phase (2 barriers/kt).
// K-partners combine via 128 KB LDS exchange before the fused epilogue.
// T1 XCD-grouped block swizzle (verified r4: FETCH 159->61 MB);
// T2 LDS XOR-swizzle (verified r3: bank conflicts 1.26e7->0);
// T4 counted vmcnt(6), 3-slot rolling LDS; T5 setprio.

typedef __attribute__((ext_vector_type(8))) short bf16x8;
typedef __attribute__((ext_vector_type(4))) float f32x4;
typedef __attribute__((ext_vector_type(8))) unsigned short ushort8;

#define BATCH 8192
#define DH    1024
#define KTOT  2048
#define NKT   32          // KTOT / 64
#define ASLOT 16384       // 256*64 shorts per A slot
#define BSLOT 8192        // 128*64 shorts per B slot
#define LDS_BYTES ((3*ASLOT + 3*BSLOT) * 2)   // 147456 (combine needs 131072)

__device__ __forceinline__ unsigned short f2bf(float f) {
    unsigned int u = __float_as_uint(f);
    u += 0x7FFFu + ((u >> 16) & 1u);   // round-to-nearest-even
    return (unsigned short)(u >> 16);
}

__device__ __forceinline__ float tanh_fast(float v) {
    float a = fabsf(v);
    float e = __expf(-2.0f * a);
    float t = (1.0f - e) / (1.0f + e);
    return v < 0.0f ? -t : t;
}

__device__ __forceinline__ void gload_lds16(const void* g, void* l) {
    __builtin_amdgcn_global_load_lds(
        (const __attribute__((address_space(1))) void*)g,
        (__attribute__((address_space(3))) void*)l, 16, 0, 0);
}

// One cast kernel for A=bf16([h|x]) (8192x2048) and W=bf16([Wh|Wx]) (1024x2048).
#define A_CHUNKS 2097152u
#define W_CHUNKS 262144u
__global__ __launch_bounds__(256) void cast_all_kernel(
    const float* __restrict__ h, const float* __restrict__ x,
    const float* __restrict__ Whw, const float* __restrict__ Wxw,
    unsigned short* __restrict__ Abf, unsigned short* __restrict__ Wbf)
{
    for (unsigned c = blockIdx.x * 256u + threadIdx.x;
         c < A_CHUNKS + W_CHUNKS; c += gridDim.x * 256u) {
        const float* src;
        unsigned short* dst;
        if (c < A_CHUNKS) {
            unsigned base = c * 8u, r = base >> 11, k = base & 2047u;
            src = (k < 1024u) ? (h + (size_t)r * 1024u + k)
                              : (x + (size_t)r * 1024u + (k - 1024u));
            dst = Abf + base;
        } else {
            unsigned c2 = c - A_CHUNKS;
            unsigned base = c2 * 8u, r = base >> 11, k = base & 2047u;
            src = (k < 1024u) ? (Whw + (size_t)r * 1024u + k)
                              : (Wxw + (size_t)r * 1024u + (k - 1024u));
            dst = Wbf + base;
        }
        const float4* s4 = (const float4*)src;
        float4 f0 = s4[0], f1 = s4[1];
        ushort8 o;
        o[0]=f2bf(f0.x); o[1]=f2bf(f0.y); o[2]=f2bf(f0.z); o[3]=f2bf(f0.w);
        o[4]=f2bf(f1.x); o[5]=f2bf(f1.y); o[6]=f2bf(f1.z); o[7]=f2bf(f1.w);
        *(ushort8*)dst = o;
    }
}

__global__ __launch_bounds__(512, 2) void lstm_gemm_kernel(
    const unsigned short* __restrict__ A,   // [8192][2048] bf16
    const unsigned short* __restrict__ W,   // [1024][2048] bf16
    const float* __restrict__ Whb, const float* __restrict__ Wxb,
    const float* __restrict__ Cin,
    float* __restrict__ Hout, float* __restrict__ Cout)
{
    extern __shared__ unsigned short smem[];
    unsigned short* sA = smem;               // 3 slots of 256x64
    unsigned short* sB = smem + 3 * ASLOT;   // 3 slots of 128x64

    const int tid  = threadIdx.x;
    const int wid  = tid >> 6;
    const int lane = tid & 63;
    const int kh = wid & 1;                  // kk-half owner
    const int wc = (wid >> 1) & 1;           // N half (64 cols)
    const int wr = wid >> 2;                 // M half (128 rows)

    // T1 XCD-grouping: XCD x gets bidM in [4x,4x+4) x all bidN (bijective on 256).
    const int orig = blockIdx.x;
    const int xcd  = orig & 7;
    const int loc  = orig >> 3;                     // 0..31
    const int bidM = xcd * 4 + (loc >> 3);          // 0..31
    const int bidN = loc & 7;                       // 0..7
    const int row0 = bidM * 256, col0 = bidN * 128;
    const int ln15 = lane & 15, hi = lane >> 4, ln7 = lane & 7;

    const unsigned short* Ag = A + (size_t)row0 * KTOT;
    const unsigned short* Bg = W + (size_t)col0 * KTOT;

    f32x4 acc[8][4] = {};

    // Stage one 128-row x 64-col unit: linear LDS dest (gload_lds lane x 16B),
    // inverse-swizzled global source (physical slot p holds logical p^(r&7)).
    auto stage = [&](const unsigned short* gbase, unsigned short* lbase) {
        #pragma unroll
        for (int j = 0; j < 2; ++j) {
            int c = j * 512 + tid;
            int r = c >> 3, p = c & 7;
            const unsigned short* g = gbase + (size_t)r * KTOT + ((p ^ (r & 7)) * 8);
            unsigned short* l = lbase + (size_t)(j * 512 + wid * 64) * 8;  // wave-uniform
            gload_lds16(g, l);
        }
    };

    // Prologue: tile 0 -> slot 0, tile 1 -> slot 1 (12 loads/thread), gate tile 0.
    stage(Ag,                           sA);
    stage(Ag + (size_t)128 * KTOT,      sA + 8192);
    stage(Bg,                           sB);
    stage(Ag + 64,                      sA + ASLOT);
    stage(Ag + (size_t)128 * KTOT + 64, sA + ASLOT + 8192);
    stage(Bg + 64,                      sB + BSLOT);
    asm volatile("s_waitcnt vmcnt(6)" ::: "memory");
    __builtin_amdgcn_s_barrier();

    const int kc = ((kh * 4 + hi) ^ ln7) * 8;   // swizzled k-byte-slot (shorts)

    int scur = 0, swr = 2;
    for (int kt = 0; kt < NKT; ++kt) {
        const unsigned short* As = sA + scur * ASLOT;
        const unsigned short* Bs = sB + scur * BSLOT;

        bf16x8 af[8], bfr[4];
        #pragma unroll
        for (int m = 0; m < 8; ++m)
            af[m] = *(const bf16x8*)(As + (wr * 128 + m * 16 + ln15) * 64 + kc);
        #pragma unroll
        for (int n = 0; n < 4; ++n)
            bfr[n] = *(const bf16x8*)(Bs + (wc * 64 + n * 16 + ln15) * 64 + kc);

        if (kt < NKT - 2) {
            const size_t kn = (size_t)(kt + 2) * 64;
            unsigned short* Aw = sA + swr * ASLOT;
            stage(Ag + kn,                           Aw);
            stage(Ag + (size_t)128 * KTOT + kn,      Aw + 8192);
            stage(Bg + kn,                           sB + swr * BSLOT);
            asm volatile("s_waitcnt vmcnt(6)" ::: "memory");
        } else if (kt == NKT - 2) {
            asm volatile("s_waitcnt vmcnt(0)" ::: "memory");
        }
        __builtin_amdgcn_s_barrier();
        asm volatile("s_waitcnt lgkmcnt(0)" ::: "memory");
        __builtin_amdgcn_sched_barrier(0);
        __builtin_amdgcn_s_setprio(1);
        #pragma unroll
        for (int m = 0; m < 8; ++m)
            #pragma unroll
            for (int n = 0; n < 4; ++n)
                acc[m][n] = __builtin_amdgcn_mfma_f32_16x16x32_bf16(
                    af[m], bfr[n], acc[m][n], 0, 0, 0);
        __builtin_amdgcn_s_setprio(0);
        __builtin_amdgcn_s_barrier();

        scur = (scur == 2) ? 0 : scur + 1;
        swr  = (swr  == 2) ? 0 : swr  + 1;
    }

    // K-combine: kh=1 waves dump acc to LDS (lane-aligned f32x4, conflict-free),
    // kh=0 partners add and run the fused epilogue.
    float* zbuf = (float*)smem;                    // 4 tiles x 8192 f32 = 128 KiB
    const int t = wr * 2 + wc;
    if (kh) {
        float* dst = zbuf + t * 8192 + lane * 4;
        #pragma unroll
        for (int m = 0; m < 8; ++m)
            #pragma unroll
            for (int n = 0; n < 4; ++n)
                *(f32x4*)(dst + (m * 4 + n) * 256) = acc[m][n];
    }
    __syncthreads();
    if (!kh) {
        const float* src = zbuf + t * 8192 + lane * 4;
        const int rlo = hi * 4;
        #pragma unroll
        for (int n = 0; n < 4; ++n) {
            const int col = col0 + wc * 64 + n * 16 + ln15;
            const float bias = Whb[col] + Wxb[col];
            #pragma unroll
            for (int m = 0; m < 8; ++m) {
                const f32x4 part = *(const f32x4*)(src + (m * 4 + n) * 256);
                #pragma unroll
                for (int j = 0; j < 4; ++j) {
                    const int row = row0 + wr * 128 + m * 16 + rlo + j;
                    const size_t off = (size_t)row * DH + col;
                    const float z = acc[m][n][j] + part[j] + bias;
                    const float s = 0.5f + 0.5f * tanh_fast(0.5f * z);  // sigmoid
                    const float g = tanh_fast(z);
                    const float cn = s * (Cin[off] + g);
                    Hout[off] = s * tanh_fast(cn);
                    Cout[off] = cn;
                }
            }
        }
    }
}

// fp32 fallback (only if workspace too small for bf16 staging)
__global__ __launch_bounds__(256) void lstm_naive_kernel(
    const float* __restrict__ x, const float* __restrict__ h,
    const float* __restrict__ c,
    const float* __restrict__ Whw, const float* __restrict__ Whb,
    const float* __restrict__ Wxw, const float* __restrict__ Wxb,
    float* __restrict__ Hout, float* __restrict__ Cout)
{
    const int idx = blockIdx.x * 256 + threadIdx.x;
    const int b = idx >> 10, n = idx & 1023;
    const float* hr = h  + (size_t)b * 1024;
    const float* xr = x  + (size_t)b * 1024;
    const float* wh = Whw + (size_t)n * 1024;
    const float* wx = Wxw + (size_t)n * 1024;
    float z = Whb[n] + Wxb[n];
    for (int k = 0; k < 1024; ++k) z += hr[k] * wh[k] + xr[k] * wx[k];
    const float s = 0.5f + 0.5f * tanh_fast(0.5f * z);
    const float g = tanh_fast(z);
    const size_t off = (size_t)b * 1024 + n;
    const float cn = s * (c[off] + g);
    Hout[off] = s * tanh_fast(cn);
    Cout[off] = cn;
}

extern "C" void kernel_launch(void* const* d_in, const int* in_sizes, int n_in,
                              void* d_out, int out_size, void* d_ws, size_t ws_size,
                              hipStream_t stream) {
    const float* x   = (const float*)d_in[0];
    const float* h   = (const float*)d_in[1];
    const float* c   = (const float*)d_in[2];
    const float* Whw = (const float*)d_in[3];
    const float* Whb = (const float*)d_in[4];
    const float* Wxw = (const float*)d_in[5];
    const float* Wxb = (const float*)d_in[6];
    float* Hout = (float*)d_out;
    float* Cout = Hout + (size_t)BATCH * DH;

    const size_t needA = (size_t)BATCH * KTOT * 2;   // 32 MiB
    const size_t needW = (size_t)DH * KTOT * 2;      //  4 MiB

    if (ws_size >= needA + needW) {
        unsigned short* Abf = (unsigned short*)d_ws;
        unsigned short* Wbf = (unsigned short*)((char*)d_ws + needA);
        cast_all_kernel<<<2304, 256, 0, stream>>>(h, x, Whw, Wxw, Abf, Wbf);
        (void)hipFuncSetAttribute((const void*)lstm_gemm_kernel,
                                  hipFuncAttributeMaxDynamicSharedMemorySize,
                                  LDS_BYTES);
        lstm_gemm_kernel<<<256, 512, LDS_BYTES, stream>>>(
            Abf, Wbf, Whb, Wxb, c, Hout, Cout);
    } else {
        lstm_naive_kernel<<<(BATCH * DH) / 256, 256, 0, stream>>>(
            x, h, c, Whw, Whb, Wxw, Wxb, Hout, Cout);
    }
}